// Round 6
// baseline (443.038 us; speedup 1.0000x reference)
//
#include <hip/hip_runtime.h>
#include <stdint.h>

// Voxelization, scales {2,4,8,1}.
//  - pow2 dims => scale-s index == scale-1 index >> log2(s), bit-exact in f32
//  - k_key: packed keys + partition s1 keys into 512 spatial buckets
//    (LDS multi-split, coalesced flush; bucket id from key>>18). Block 0 also
//    zeroes the chunkSums words that need init.
//  - k_bucket: per bucket, build 32KB s1 region in LDS (LDS atomicOr) and
//    derive s2/s4/s8 regions in-LDS; emits per-chunk popcount sums; zeroes
//    pad chunks. LAST block (completion counter + threadfence) runs the
//    chunk-sum scan in-place (k_scanB dispatch deleted).
//  - rank(key) via popcount-prefix; bitmap+prefix interleaved as uint2 pairs
//  - k_out (R9): R4-proven per-scale write sections (batch-slicing of R8
//    REVERTED: extra keys re-reads + de-coalesced sparse inv stores cost more
//    than the L3 fills saved). R9: 4 points/thread via uint4 keys load --
//    4 independent pairs gathers in flight, 64B contiguous coors stores.
// Dispatches: memset(bucketCount+counter), key, bucket(+scan), pref, out. (5)

#define CHUNK 4096
#define NB    1174
#define TOTALW 4808704
// region word offsets, scale order {2,4,8,1}; chunk boundaries 129,146,149
#define R_S2 0
#define R_S4 528384
#define R_S8 598016
#define R_S1 610304
// pad chunks (zeroed in k_bucket, never written by data paths)
#define PAD0 524288
#define PAD1 593920
#define PAD2 606208
#define PAD3 4804608
// bucketing: 512 buckets, each covers 2^18 s1 bits = 8192 words = 8 x1-slices
#define NBUCKET 512
#define BCAP 5120
// 1024 blocks x 2048 points, 8 keys/thread
#define KEYBLOCKS 1024
#define ROUND 2048
#define KPT 8

__device__ __forceinline__ uint32_t cmp2(uint32_t w) {
  // result bit i = w[2i] | w[2i+1]  (32->16; also 16->8 with zero upper)
  w = (w | (w >> 1)) & 0x55555555u;
  w = (w | (w >> 1)) & 0x33333333u;
  w = (w | (w >> 2)) & 0x0F0F0F0Fu;
  w = (w | (w >> 4)) & 0x00FF00FFu;
  w = (w | (w >> 8)) & 0x0000FFFFu;
  return w;
}

// ---- phase 1: keys + bucket partition ----
__global__ __launch_bounds__(256) void k_key(
    const float* __restrict__ pts, const int* __restrict__ bidx, int n,
    uint32_t* __restrict__ keys,
    uint32_t* __restrict__ bucketCount, uint32_t* __restrict__ bucketData,
    uint32_t* __restrict__ chunkSums) {
  __shared__ uint32_t cnt[NBUCKET], inc[NBUCKET], pos[NBUCKET], gpos[NBUCKET];
  __shared__ uint32_t shs[256];
  __shared__ uint32_t scratch[ROUND];
  int t = threadIdx.x;
  int base = blockIdx.x * ROUND;

  // init the chunkSums words k_bucket accumulates into (earlier dispatch than
  // k_bucket -> ordering guaranteed by the stream)
  if (blockIdx.x == 0) {
    if (t < 149) chunkSums[t] = 0;
    if (t == 149) chunkSums[1173] = 0;
  }

  cnt[t] = 0; cnt[t + 256] = 0;
  pos[t] = 0; pos[t + 256] = 0;
  __syncthreads();

  uint32_t myKey[KPT];
  int myBk[KPT];
#pragma unroll
  for (int k = 0; k < KPT; k++) {
    int j = base + k * 256 + t;
    myBk[k] = -1;
    if (j < n) {
      float px = pts[3 * j + 0];
      float py = pts[3 * j + 1];
      float pz = pts[3 * j + 2];
      int b = bidx[j];
      // exact reference arithmetic at scale 1 (f32 mul, add, div, trunc)
      int x1 = (int)((512.0f * (px + 51.2f)) / 102.4f);
      int y1 = (int)((512.0f * (py + 51.2f)) / 102.4f);
      int z1 = (int)((64.0f * (pz + 4.0f)) / 6.4f);
      keys[j] = ((uint32_t)b << 27) | ((uint32_t)x1 << 17) | ((uint32_t)y1 << 7) | (uint32_t)z1;
      uint32_t s1k = (uint32_t)(((b * 512 + x1) * 512 + y1) * 64 + z1);
      if (s1k < (1u << 27)) {  // always true for in-spec inputs; OOB-guard only
        int bk = (int)(s1k >> 18);
        myBk[k] = bk;
        myKey[k] = s1k;
        atomicAdd(&cnt[bk], 1u);
      }
    }
  }
  __syncthreads();

  // global reservation (cnt final)
  uint32_t c0 = cnt[2 * t], c1 = cnt[2 * t + 1];
  gpos[2 * t] = c0 ? atomicAdd(&bucketCount[2 * t], c0) : 0u;
  gpos[2 * t + 1] = c1 ? atomicAdd(&bucketCount[2 * t + 1], c1) : 0u;
  // inclusive scan of cnt -> inc (pairwise + 256-scan)
  uint32_t s = c0 + c1;
  shs[t] = s;
  __syncthreads();
  for (int off = 1; off < 256; off <<= 1) {
    uint32_t add = (t >= off) ? shs[t - off] : 0u;
    __syncthreads();
    shs[t] += add;
    __syncthreads();
  }
  inc[2 * t] = shs[t] - s + c0;
  inc[2 * t + 1] = shs[t];
  __syncthreads();
  uint32_t total = shs[255];

  // scatter into bucket-contiguous LDS scratch
#pragma unroll
  for (int k = 0; k < KPT; k++) {
    if (myBk[k] >= 0) {
      int bk = myBk[k];
      uint32_t slot = inc[bk] - cnt[bk] + atomicAdd(&pos[bk], 1u);
      scratch[slot] = myKey[k];
    }
  }
  __syncthreads();

  // flush: consecutive p -> contiguous global per bucket; bucket id from key
#pragma unroll
  for (int m = 0; m < KPT; m++) {
    uint32_t p = (uint32_t)(m * 256 + t);
    if (p < total) {
      uint32_t kk = scratch[p];
      int lo = (int)(kk >> 18);
      uint32_t lidx = p - (inc[lo] - cnt[lo]);
      uint32_t g = gpos[lo] + lidx;
      if (g < BCAP) bucketData[(size_t)lo * BCAP + g] = kk;
    }
  }
}

// block tree-reduction; valid result on all threads; shR reusable after return
__device__ __forceinline__ uint32_t blockReduce(uint32_t v, uint32_t* shR, int t) {
  shR[t] = v;
  __syncthreads();
  for (int off = 128; off > 0; off >>= 1) {
    if (t < off) shR[t] += shR[t + off];
    __syncthreads();
  }
  uint32_t r = shR[0];
  __syncthreads();
  return r;
}

// ---- phase 2: per-bucket LDS bitmap build + downsample + chunk sums + scan ----
__global__ __launch_bounds__(256) void k_bucket(
    uint32_t* __restrict__ bucketCount, const uint32_t* __restrict__ bucketData,
    uint32_t* __restrict__ bitmap, uint32_t* __restrict__ chunkSums,
    long long* __restrict__ devOff, uint32_t* __restrict__ devRank, long long fiveN) {
  __shared__ uint32_t s1L[8192];
  __shared__ uint32_t s2L[1024];
  __shared__ uint32_t s4L[128];
  __shared__ uint32_t shR[256];
  __shared__ uint32_t shB[3];
  __shared__ uint32_t lastFlag;
  int bk = blockIdx.x, t = threadIdx.x;

  uint4 z4 = make_uint4(0, 0, 0, 0);
  for (int i = t; i < 2048; i += 256) ((uint4*)s1L)[i] = z4;

  // zero the 4 pad chunks (blocks 0..3); everything else is fully overwritten
  if (bk < 4) {
    const int pads[4] = {PAD0, PAD1, PAD2, PAD3};
    uint4* pz = (uint4*)(bitmap + pads[bk]);
    for (int i = t; i < 1024; i += 256) pz[i] = z4;
  }
  __syncthreads();

  uint32_t c = bucketCount[bk];
  if (c > BCAP) c = BCAP;
  const uint32_t* src = bucketData + (size_t)bk * BCAP;
  for (uint32_t i = t; i < c; i += 256) {
    uint32_t key = src[i];
    uint32_t local = key & 0x3FFFFu;  // 2^18 bits per bucket
    atomicOr(&s1L[local >> 5], 1u << (local & 31u));
  }
  __syncthreads();

  // write s1 region (coalesced) + accumulate per-half-region popcounts
  uint4* g1 = (uint4*)(bitmap + R_S1 + (size_t)bk * 8192);
  uint32_t pc1a = 0, pc1b = 0;
  for (int i = t; i < 2048; i += 256) {
    uint4 v = ((uint4*)s1L)[i];
    g1[i] = v;
    uint32_t pc = __popc(v.x) + __popc(v.y) + __popc(v.z) + __popc(v.w);
    if (i < 1024) pc1a += pc; else pc1b += pc;
  }

  // s2 from s1 (local layout: s1 word = (x1rel*512 + y1)*2 + h, x1rel in [0,8))
  for (int i = t; i < 1024; i += 256) {
    int x2r = i >> 8, Y2 = i & 255;
    int a = (2 * x2r * 512 + 2 * Y2) * 2;
    int b2 = ((2 * x2r + 1) * 512 + 2 * Y2) * 2;
    uint32_t Ax = s1L[a], Ay = s1L[a + 1], Az = s1L[a + 2], Aw = s1L[a + 3];
    uint32_t Bx = s1L[b2], By = s1L[b2 + 1], Bz = s1L[b2 + 2], Bw = s1L[b2 + 3];
    s2L[i] = cmp2(Ax | Az | Bx | Bz) | (cmp2(Ay | Aw | By | Bw) << 16);
  }
  __syncthreads();
  uint32_t pc2 = 0;
  for (int i = t; i < 1024; i += 256) {
    uint32_t v = s2L[i];
    bitmap[R_S2 + (size_t)bk * 1024 + i] = v;
    pc2 += __popc(v);
  }

  // s4 from s2 (s2 local: x2rel*256 + y2, x2rel in [0,4))
  uint32_t pc4 = 0;
  if (t < 128) {
    int x4r = t >> 6, kk = t & 63;
    int a = (2 * x4r) * 256 + 4 * kk;
    int b4 = (2 * x4r + 1) * 256 + 4 * kk;
    uint32_t A0 = s2L[a], A1 = s2L[a + 1], A2 = s2L[a + 2], A3 = s2L[a + 3];
    uint32_t B0 = s2L[b4], B1 = s2L[b4 + 1], B2 = s2L[b4 + 2], B3 = s2L[b4 + 3];
    uint32_t v = cmp2(A0 | A1 | B0 | B1) | (cmp2(A2 | A3 | B2 | B3) << 16);
    s4L[t] = v;
    pc4 = __popc(v);
  }
  __syncthreads();
  if (t < 128) bitmap[R_S4 + (size_t)bk * 128 + t] = s4L[t];

  // s8 from s4 (s4 local: x4rel*64 + kk, x4rel in {0,1})
  uint32_t pc8 = 0;
  if (t < 16) {
    uint32_t res = 0;
#pragma unroll
    for (int j = 0; j < 4; j++) {
      uint32_t u = s4L[4 * t + j] | s4L[64 + 4 * t + j];
      u = (u | (u >> 16)) & 0xFFFFu;
      res |= cmp2(u) << (8 * j);
    }
    bitmap[R_S8 + (size_t)bk * 16 + t] = res;
    pc8 = __popc(res);
  }

  // chunk sums: s1 chunks are bucket-exclusive (plain store); s2/s4/s8 chunks
  // span 4/32/256 buckets (atomicAdd partials)
  uint32_t S1a = blockReduce(pc1a, shR, t);
  uint32_t S1b = blockReduce(pc1b, shR, t);
  uint32_t S2 = blockReduce(pc2, shR, t);
  uint32_t S4 = blockReduce(pc4, shR, t);
  uint32_t S8 = blockReduce(pc8, shR, t);
  if (t == 0) {
    chunkSums[149 + 2 * bk] = S1a;
    chunkSums[150 + 2 * bk] = S1b;
    atomicAdd(&chunkSums[bk >> 2], S2);
    atomicAdd(&chunkSums[129 + (bk >> 5)], S4);
    atomicAdd(&chunkSums[146 + (bk >> 8)], S8);
  }

  // ---- last-block chunk-sum scan (replaces k_scanB dispatch) ----
  if (t == 0) {
    __threadfence();  // release all chunkSums stores device-wide
    lastFlag = (atomicAdd(&bucketCount[NBUCKET], 1u) == NBUCKET - 1) ? 1u : 0u;
  }
  __syncthreads();
  if (lastFlag) {
    __threadfence();  // acquire other blocks' chunkSums stores
    uint32_t v[8];
    uint32_t s = 0;
#pragma unroll
    for (int k = 0; k < 8; k++) {
      int idx = t * 8 + k;
      uint32_t x = (idx < NB) ? chunkSums[idx] : 0u;
      v[k] = x;
      s += x;
    }
    shR[t] = s;
    __syncthreads();
    for (int off = 1; off < 256; off <<= 1) {
      uint32_t add = (t >= off) ? shR[t - off] : 0u;
      __syncthreads();
      shR[t] += add;
      __syncthreads();
    }
    uint32_t run = shR[t] - s;
#pragma unroll
    for (int k = 0; k < 8; k++) {
      int idx = t * 8 + k;
      if (idx < NB) chunkSums[idx] = run;
      if (idx == 129) shB[0] = run;
      if (idx == 146) shB[1] = run;
      if (idx == 149) shB[2] = run;
      run += v[k];
    }
    __syncthreads();
    if (t == 0) {
      uint32_t tot = shR[255];
      uint32_t T0 = shB[0];
      uint32_t T1 = shB[1] - shB[0];
      uint32_t T2 = shB[2] - shB[1];
      uint32_t T3 = tot - shB[2];
      devOff[0] = 0;
      devOff[1] = devOff[0] + fiveN + 4LL * T0;
      devOff[2] = devOff[1] + fiveN + 4LL * T1;
      devOff[3] = devOff[2] + fiveN + 4LL * T2;
      devOff[4] = devOff[3] + fiveN + 4LL * T3;
      devRank[0] = 0;
      devRank[1] = shB[0];
      devRank[2] = shB[1];
      devRank[3] = shB[2];
    }
  }
}

__global__ __launch_bounds__(256) void k_pref(
    const uint32_t* __restrict__ bitmap, const uint32_t* __restrict__ blockSums,
    uint2* __restrict__ pairs) {
  __shared__ uint32_t sh[256];
  int t = threadIdx.x;
  size_t w0 = (size_t)blockIdx.x * CHUNK + t * 16;
  const uint4* bp = (const uint4*)(bitmap + w0);
  uint4 words[4];
  uint32_t s = 0;
#pragma unroll
  for (int k = 0; k < 4; k++) {
    uint4 v = bp[k];
    words[k] = v;
    s += __popc(v.x) + __popc(v.y) + __popc(v.z) + __popc(v.w);
  }
  sh[t] = s;
  __syncthreads();
  for (int off = 1; off < 256; off <<= 1) {
    uint32_t add = (t >= off) ? sh[t - off] : 0u;
    __syncthreads();
    sh[t] += add;
    __syncthreads();
  }
  uint32_t run = blockSums[blockIdx.x] + (sh[t] - s);
  uint4* pp = (uint4*)(pairs + w0);
#pragma unroll
  for (int k = 0; k < 4; k++) {
    uint4 o1, o2;
    o1.x = words[k].x; o1.y = run; run += __popc(words[k].x);
    o1.z = words[k].y; o1.w = run; run += __popc(words[k].y);
    o2.x = words[k].z; o2.y = run; run += __popc(words[k].z);
    o2.z = words[k].w; o2.w = run; run += __popc(words[k].w);
    pp[2 * k] = o1;
    pp[2 * k + 1] = o2;
  }
}

// bit-decode of one word's set bits -> unique coors rows
template <int LZ, int LYZ, int LB, int MZ, int MY, int MX, int RG, int SCALE_IDX>
__device__ __forceinline__ void uniq_region(
    uint32_t w, uint32_t wd, uint32_t pf, uint32_t rankBase,
    const long long* __restrict__ devOff, int* __restrict__ out, long long fiveN) {
  uint32_t pos = pf - rankBase;
  long long base = devOff[SCALE_IDX] + fiveN;
  uint32_t local = w - (uint32_t)RG;
  while (wd) {
    int bit = __ffs(wd) - 1;
    wd &= wd - 1u;
    uint32_t key = (local << 5) + (uint32_t)bit;
    int z = (int)(key & (uint32_t)MZ);
    int y = (int)((key >> LZ) & (uint32_t)MY);
    int x = (int)((key >> LYZ) & (uint32_t)MX);
    int bb = (int)(key >> LB);
    *(int4*)(out + base + 4LL * pos) = make_int4(bb, z, y, x);
    pos++;
  }
}

// process one point for scale params; emits full_coors int4 + inverse int
__device__ __forceinline__ void write_point(
    uint32_t p, int j, int sh, int sx, int sz, int rg,
    long long o, uint32_t rnk, const uint2* __restrict__ pairs,
    int* __restrict__ out, long long fourN) {
  int b = (int)(p >> 27);
  int x1 = (int)((p >> 17) & 1023u);
  int y1 = (int)((p >> 7) & 1023u);
  int z1 = (int)(p & 127u);
  int xi = x1 >> sh, yi = y1 >> sh, zi = z1 >> sh;
  uint32_t key = (uint32_t)(((b * sx + xi) * sx + yi) * sz + zi);
  uint2 pr = pairs[rg + (key >> 5)];
  *(int4*)(out + o + 4LL * j) = make_int4(b, xi, yi, zi);
  uint32_t inv = pr.y + __popc(pr.x & ((1u << (key & 31u)) - 1u)) - rnk;
  out[o + fourN + j] = (int)inv;
}

// ---- merged outputs (R9) ----
// blocks [0, 4*NW4):  per-scale write sections (s1,s2,s4,s8), 4 pts/thread
//                     via uint4 keys load (4 gathers in flight)
// blocks [4*NW4, +TOTALW/256): unique-row decode
__global__ __launch_bounds__(256) void k_out(
    const uint32_t* __restrict__ keys, int n, const uint2* __restrict__ pairs,
    const uint32_t* __restrict__ devRank, const long long* __restrict__ devOff,
    int* __restrict__ out, long long fourN, long long fiveN, int NW4) {
  int bid = blockIdx.x;
  int t = threadIdx.x;
  if (bid < 4 * NW4) {
    int sec = bid / NW4;
    int wb = bid - sec * NW4;
    const int SCI[4] = {3, 0, 1, 2};  // section -> scale idx (s1 first)
    const int SX[4] = {256, 128, 64, 512};   // SY == SX for all scales
    const int SZ[4] = {32, 16, 8, 64};
    const int SH[4] = {1, 2, 3, 0};
    const int RG[4] = {R_S2, R_S4, R_S8, R_S1};
    int i = SCI[sec];
    int sh = SH[i], sx = SX[i], sz = SZ[i], rg = RG[i];
    long long o = devOff[i];
    uint32_t rnk = devRank[i];
    int j0 = wb * 1024 + 4 * t;
    if (j0 + 3 < n) {
      uint4 kv = *(const uint4*)(keys + j0);
      write_point(kv.x, j0 + 0, sh, sx, sz, rg, o, rnk, pairs, out, fourN);
      write_point(kv.y, j0 + 1, sh, sx, sz, rg, o, rnk, pairs, out, fourN);
      write_point(kv.z, j0 + 2, sh, sx, sz, rg, o, rnk, pairs, out, fourN);
      write_point(kv.w, j0 + 3, sh, sx, sz, rg, o, rnk, pairs, out, fourN);
    } else {
      for (int j = j0; j < n; j++)
        write_point(keys[j], j, sh, sx, sz, rg, o, rnk, pairs, out, fourN);
    }
  } else {
    uint32_t w = (uint32_t)(bid - 4 * NW4) * 256 + t;  // < TOTALW, regions block-aligned
    uint2 pr = pairs[w];
    if (!pr.x) return;
    if (w < R_S4) {
      uniq_region<5, 13, 21, 31, 255, 255, R_S2, 0>(w, pr.x, pr.y, devRank[0], devOff, out, fiveN);
    } else if (w < R_S8) {
      uniq_region<4, 11, 18, 15, 127, 127, R_S4, 1>(w, pr.x, pr.y, devRank[1], devOff, out, fiveN);
    } else if (w < R_S1) {
      uniq_region<3, 9, 15, 7, 63, 63, R_S8, 2>(w, pr.x, pr.y, devRank[2], devOff, out, fiveN);
    } else {
      uniq_region<6, 15, 24, 63, 511, 511, R_S1, 3>(w, pr.x, pr.y, devRank[3], devOff, out, fiveN);
    }
  }
}

extern "C" void kernel_launch(void* const* d_in, const int* in_sizes, int n_in,
                              void* d_out, int out_size, void* d_ws, size_t ws_size,
                              hipStream_t stream) {
  const float* pts = (const float*)d_in[0];
  const int* bidx = (const int*)d_in[1];
  int n = in_sizes[0] / 3;
  int* out = (int*)d_out;

  char* ws = (char*)d_ws;
  long long* devOff = (long long*)ws;                          // 5 * 8 B
  uint32_t* devRank = (uint32_t*)(ws + 64);                    // 4 * 4 B
  uint32_t* chunkSums = (uint32_t*)(ws + 256);                 // NB * 4 B
  uint32_t* bucketCount = (uint32_t*)(ws + 5120);              // (512+1) * 4 B
  uint32_t* bitmap = (uint32_t*)(ws + 8192);                   // TOTALW * 4 B
  uint2* pairs = (uint2*)(ws + 19243008);                      // TOTALW * 8 B
  uint32_t* keys = (uint32_t*)(ws + 57712640);                 // n * 4 B
  uint32_t* bucketData = (uint32_t*)(ws + 65712640);           // 512 * BCAP * 4 B

  const long long fourN = 4LL * n, fiveN = 5LL * n;
  const int NW4 = (n + 1023) / 1024;

  hipMemsetAsync(bucketCount, 0, (NBUCKET + 1) * 4, stream);
  hipLaunchKernelGGL(k_key, dim3(KEYBLOCKS), dim3(256), 0, stream,
                     pts, bidx, n, keys, bucketCount, bucketData, chunkSums);
  hipLaunchKernelGGL(k_bucket, dim3(NBUCKET), dim3(256), 0, stream,
                     bucketCount, bucketData, bitmap, chunkSums, devOff, devRank, fiveN);
  hipLaunchKernelGGL(k_pref, dim3(NB), dim3(256), 0, stream, bitmap, chunkSums, pairs);
  hipLaunchKernelGGL(k_out, dim3(4 * NW4 + TOTALW / 256), dim3(256), 0, stream,
                     keys, n, pairs, devRank, devOff, out, fourN, fiveN, NW4);
}

// Round 7
// 427.366 us; speedup vs baseline: 1.0367x; 1.0367x over previous
//
#include <hip/hip_runtime.h>
#include <stdint.h>

// Voxelization, scales {2,4,8,1}.
//  - pow2 dims => scale-s index == scale-1 index >> log2(s), bit-exact in f32
//  - k_key: packed keys + partition s1 keys into 512 spatial buckets.
//  - k_bucket: per bucket, build 32KB s1 region in LDS; derive s2/s4/s8
//    in-LDS; emits per-chunk popcount sums. R10: emits s1 PAIRS directly
//    (word bits + chunk-LOCAL prefix via 256-scan, reset at thread 128 =
//    chunk boundary) -- s1 bitmap never written, k_pref's s1 leg deleted
//    (-17MB write, -17MB read, k_pref 1174->149 blocks).
//  - k_scanB: separate 1-block dispatch (R4-proven config).
//  - k_pref: s2/s4/s8 chunks only (global prefixes).
//  - k_out: R4-proven per-scale sections, 2 pts/thread (coalesced stores;
//    R9's 4pt uint4 de-coalesced stores, regressed). s1 consumers add
//    chunkSums[chunk] to the local prefix (4.7KB table, L1-resident).
// Dispatches: memset(bucketCount), key, bucket, scanB, pref, out. (6)

#define CHUNK 4096
#define NB    1174
#define TOTALW 4808704
// region word offsets, scale order {2,4,8,1}; chunk boundaries 129,146,149
#define R_S2 0
#define R_S4 528384
#define R_S8 598016
#define R_S1 610304
// pad chunks: s2/s4/s8 pads zeroed in bitmap; s1 pad (PAD3) zeroed in PAIRS
#define PAD0 524288
#define PAD1 593920
#define PAD2 606208
#define PAD3 4804608
// bucketing: 512 buckets, each covers 2^18 s1 bits = 8192 words = 2 chunks
#define NBUCKET 512
#define BCAP 5120
// 1024 blocks x 2048 points, 8 keys/thread
#define KEYBLOCKS 1024
#define ROUND 2048
#define KPT 8
// k_pref covers only s2/s4/s8 (+pads): chunks 0..148
#define NB_SMALL 149

__device__ __forceinline__ uint32_t cmp2(uint32_t w) {
  // result bit i = w[2i] | w[2i+1]  (32->16; also 16->8 with zero upper)
  w = (w | (w >> 1)) & 0x55555555u;
  w = (w | (w >> 1)) & 0x33333333u;
  w = (w | (w >> 2)) & 0x0F0F0F0Fu;
  w = (w | (w >> 4)) & 0x00FF00FFu;
  w = (w | (w >> 8)) & 0x0000FFFFu;
  return w;
}

// ---- phase 1: keys + bucket partition ----
__global__ __launch_bounds__(256) void k_key(
    const float* __restrict__ pts, const int* __restrict__ bidx, int n,
    uint32_t* __restrict__ keys,
    uint32_t* __restrict__ bucketCount, uint32_t* __restrict__ bucketData,
    uint32_t* __restrict__ chunkSums) {
  __shared__ uint32_t cnt[NBUCKET], inc[NBUCKET], pos[NBUCKET], gpos[NBUCKET];
  __shared__ uint32_t shs[256];
  __shared__ uint32_t scratch[ROUND];
  int t = threadIdx.x;
  int base = blockIdx.x * ROUND;

  // init the chunkSums words k_bucket accumulates into (earlier dispatch than
  // k_bucket -> ordering guaranteed by the stream)
  if (blockIdx.x == 0) {
    if (t < 149) chunkSums[t] = 0;
    if (t == 149) chunkSums[1173] = 0;
  }

  cnt[t] = 0; cnt[t + 256] = 0;
  pos[t] = 0; pos[t + 256] = 0;
  __syncthreads();

  uint32_t myKey[KPT];
  int myBk[KPT];
#pragma unroll
  for (int k = 0; k < KPT; k++) {
    int j = base + k * 256 + t;
    myBk[k] = -1;
    if (j < n) {
      float px = pts[3 * j + 0];
      float py = pts[3 * j + 1];
      float pz = pts[3 * j + 2];
      int b = bidx[j];
      // exact reference arithmetic at scale 1 (f32 mul, add, div, trunc)
      int x1 = (int)((512.0f * (px + 51.2f)) / 102.4f);
      int y1 = (int)((512.0f * (py + 51.2f)) / 102.4f);
      int z1 = (int)((64.0f * (pz + 4.0f)) / 6.4f);
      keys[j] = ((uint32_t)b << 27) | ((uint32_t)x1 << 17) | ((uint32_t)y1 << 7) | (uint32_t)z1;
      uint32_t s1k = (uint32_t)(((b * 512 + x1) * 512 + y1) * 64 + z1);
      if (s1k < (1u << 27)) {  // always true for in-spec inputs; OOB-guard only
        int bk = (int)(s1k >> 18);
        myBk[k] = bk;
        myKey[k] = s1k;
        atomicAdd(&cnt[bk], 1u);
      }
    }
  }
  __syncthreads();

  // global reservation (cnt final)
  uint32_t c0 = cnt[2 * t], c1 = cnt[2 * t + 1];
  gpos[2 * t] = c0 ? atomicAdd(&bucketCount[2 * t], c0) : 0u;
  gpos[2 * t + 1] = c1 ? atomicAdd(&bucketCount[2 * t + 1], c1) : 0u;
  // inclusive scan of cnt -> inc (pairwise + 256-scan)
  uint32_t s = c0 + c1;
  shs[t] = s;
  __syncthreads();
  for (int off = 1; off < 256; off <<= 1) {
    uint32_t add = (t >= off) ? shs[t - off] : 0u;
    __syncthreads();
    shs[t] += add;
    __syncthreads();
  }
  inc[2 * t] = shs[t] - s + c0;
  inc[2 * t + 1] = shs[t];
  __syncthreads();
  uint32_t total = shs[255];

  // scatter into bucket-contiguous LDS scratch
#pragma unroll
  for (int k = 0; k < KPT; k++) {
    if (myBk[k] >= 0) {
      int bk = myBk[k];
      uint32_t slot = inc[bk] - cnt[bk] + atomicAdd(&pos[bk], 1u);
      scratch[slot] = myKey[k];
    }
  }
  __syncthreads();

  // flush: consecutive p -> contiguous global per bucket; bucket id from key
#pragma unroll
  for (int m = 0; m < KPT; m++) {
    uint32_t p = (uint32_t)(m * 256 + t);
    if (p < total) {
      uint32_t kk = scratch[p];
      int lo = (int)(kk >> 18);
      uint32_t lidx = p - (inc[lo] - cnt[lo]);
      uint32_t g = gpos[lo] + lidx;
      if (g < BCAP) bucketData[(size_t)lo * BCAP + g] = kk;
    }
  }
}

// block tree-reduction; valid result on all threads; shR reusable after return
__device__ __forceinline__ uint32_t blockReduce(uint32_t v, uint32_t* shR, int t) {
  shR[t] = v;
  __syncthreads();
  for (int off = 128; off > 0; off >>= 1) {
    if (t < off) shR[t] += shR[t + off];
    __syncthreads();
  }
  uint32_t r = shR[0];
  __syncthreads();
  return r;
}

// ---- phase 2: per-bucket LDS bitmap build + downsample + chunk sums ----
// R10: s1 PAIRS (bits + chunk-local prefix) emitted here; s1 bitmap skipped.
__global__ __launch_bounds__(256) void k_bucket(
    const uint32_t* __restrict__ bucketCount, const uint32_t* __restrict__ bucketData,
    uint32_t* __restrict__ bitmap, uint32_t* __restrict__ chunkSums,
    uint2* __restrict__ pairs) {
  __shared__ uint32_t s1L[8192];
  __shared__ uint32_t s2L[1024];
  __shared__ uint32_t s4L[128];
  __shared__ uint32_t shR[256];
  int bk = blockIdx.x, t = threadIdx.x;

  uint4 z4 = make_uint4(0, 0, 0, 0);
  for (int i = t; i < 2048; i += 256) ((uint4*)s1L)[i] = z4;

  // zero s2/s4/s8 pad chunks in bitmap (blocks 0..2); zero s1-pad PAIRS (blk 3)
  if (bk < 3) {
    const int pads[3] = {PAD0, PAD1, PAD2};
    uint4* pz = (uint4*)(bitmap + pads[bk]);
    for (int i = t; i < 1024; i += 256) pz[i] = z4;
  } else if (bk == 3) {
    uint4* pz = (uint4*)(pairs + PAD3);  // chunk 1173: 4096 uint2 = 2048 uint4
    for (int i = t; i < 2048; i += 256) pz[i] = z4;
  }
  __syncthreads();

  uint32_t c = bucketCount[bk];
  if (c > BCAP) c = BCAP;
  const uint32_t* src = bucketData + (size_t)bk * BCAP;
  for (uint32_t i = t; i < c; i += 256) {
    uint32_t key = src[i];
    uint32_t local = key & 0x3FFFFu;  // 2^18 bits per bucket
    atomicOr(&s1L[local >> 5], 1u << (local & 31u));
  }
  __syncthreads();

  // ---- s1 pairs: thread t owns words [32t, 32t+32) (uint4 idx 8t..8t+7);
  // threads 0..127 = chunk A (words 0..4095), 128..255 = chunk B. ----
  uint32_t wsum = 0;
#pragma unroll
  for (int m = 0; m < 8; m++) {
    uint4 v = ((uint4*)s1L)[8 * t + m];
    wsum += __popc(v.x) + __popc(v.y) + __popc(v.z) + __popc(v.w);
  }
  shR[t] = wsum;
  __syncthreads();
  for (int off = 1; off < 256; off <<= 1) {
    uint32_t add = (t >= off) ? shR[t - off] : 0u;
    __syncthreads();
    shR[t] += add;
    __syncthreads();
  }
  uint32_t S1a = shR[127];
  uint32_t S1b = shR[255] - S1a;
  uint32_t run = shR[t] - wsum;       // exclusive prefix
  if (t >= 128) run -= S1a;           // reset at chunk boundary
  __syncthreads();
  {
    uint4* pb = (uint4*)(pairs + (R_S1 + (size_t)bk * 8192));
#pragma unroll
    for (int m = 0; m < 8; m++) {
      uint4 v = ((uint4*)s1L)[8 * t + m];
      uint32_t r0 = run;               uint32_t p0 = __popc(v.x);
      uint32_t r1 = r0 + p0;           uint32_t p1 = __popc(v.y);
      uint32_t r2 = r1 + p1;           uint32_t p2 = __popc(v.z);
      uint32_t r3 = r2 + p2;           run = r3 + __popc(v.w);
      int q = (32 * t + 4 * m) >> 1;   // uint4 index into pairs
      pb[q + 0] = make_uint4(v.x, r0, v.y, r1);
      pb[q + 1] = make_uint4(v.z, r2, v.w, r3);
    }
  }

  // s2 from s1 (local layout: s1 word = (x1rel*512 + y1)*2 + h, x1rel in [0,8))
  for (int i = t; i < 1024; i += 256) {
    int x2r = i >> 8, Y2 = i & 255;
    int a = (2 * x2r * 512 + 2 * Y2) * 2;
    int b2 = ((2 * x2r + 1) * 512 + 2 * Y2) * 2;
    uint32_t Ax = s1L[a], Ay = s1L[a + 1], Az = s1L[a + 2], Aw = s1L[a + 3];
    uint32_t Bx = s1L[b2], By = s1L[b2 + 1], Bz = s1L[b2 + 2], Bw = s1L[b2 + 3];
    s2L[i] = cmp2(Ax | Az | Bx | Bz) | (cmp2(Ay | Aw | By | Bw) << 16);
  }
  __syncthreads();
  uint32_t pc2 = 0;
  for (int i = t; i < 1024; i += 256) {
    uint32_t v = s2L[i];
    bitmap[R_S2 + (size_t)bk * 1024 + i] = v;
    pc2 += __popc(v);
  }

  // s4 from s2 (s2 local: x2rel*256 + y2, x2rel in [0,4))
  uint32_t pc4 = 0;
  if (t < 128) {
    int x4r = t >> 6, kk = t & 63;
    int a = (2 * x4r) * 256 + 4 * kk;
    int b4 = (2 * x4r + 1) * 256 + 4 * kk;
    uint32_t A0 = s2L[a], A1 = s2L[a + 1], A2 = s2L[a + 2], A3 = s2L[a + 3];
    uint32_t B0 = s2L[b4], B1 = s2L[b4 + 1], B2 = s2L[b4 + 2], B3 = s2L[b4 + 3];
    uint32_t v = cmp2(A0 | A1 | B0 | B1) | (cmp2(A2 | A3 | B2 | B3) << 16);
    s4L[t] = v;
    pc4 = __popc(v);
  }
  __syncthreads();
  if (t < 128) bitmap[R_S4 + (size_t)bk * 128 + t] = s4L[t];

  // s8 from s4 (s4 local: x4rel*64 + kk, x4rel in {0,1})
  uint32_t pc8 = 0;
  if (t < 16) {
    uint32_t res = 0;
#pragma unroll
    for (int j = 0; j < 4; j++) {
      uint32_t u = s4L[4 * t + j] | s4L[64 + 4 * t + j];
      u = (u | (u >> 16)) & 0xFFFFu;
      res |= cmp2(u) << (8 * j);
    }
    bitmap[R_S8 + (size_t)bk * 16 + t] = res;
    pc8 = __popc(res);
  }

  // chunk sums: s1 chunks are bucket-exclusive (plain store); s2/s4/s8 chunks
  // span 4/32/256 buckets (atomicAdd partials)
  uint32_t S2 = blockReduce(pc2, shR, t);
  uint32_t S4 = blockReduce(pc4, shR, t);
  uint32_t S8 = blockReduce(pc8, shR, t);
  if (t == 0) {
    chunkSums[149 + 2 * bk] = S1a;
    chunkSums[150 + 2 * bk] = S1b;
    atomicAdd(&chunkSums[bk >> 2], S2);
    atomicAdd(&chunkSums[129 + (bk >> 5)], S4);
    atomicAdd(&chunkSums[146 + (bk >> 8)], S8);
  }
}

// ---- scan / rank infrastructure ----
__global__ __launch_bounds__(256) void k_scanB(
    uint32_t* blockSums, long long* devOff, uint32_t* devRank, long long fiveN) {
  __shared__ uint32_t sh[256];
  __shared__ uint32_t shB[3];
  int t = threadIdx.x;
  uint32_t v[8];
  uint32_t s = 0;
#pragma unroll
  for (int k = 0; k < 8; k++) {
    int idx = t * 8 + k;
    uint32_t x = (idx < NB) ? blockSums[idx] : 0u;
    v[k] = x;
    s += x;
  }
  sh[t] = s;
  __syncthreads();
  for (int off = 1; off < 256; off <<= 1) {
    uint32_t add = (t >= off) ? sh[t - off] : 0u;
    __syncthreads();
    sh[t] += add;
    __syncthreads();
  }
  uint32_t run = sh[t] - s;
#pragma unroll
  for (int k = 0; k < 8; k++) {
    int idx = t * 8 + k;
    if (idx < NB) blockSums[idx] = run;
    if (idx == 129) shB[0] = run;
    if (idx == 146) shB[1] = run;
    if (idx == 149) shB[2] = run;
    run += v[k];
  }
  __syncthreads();
  if (t == 0) {
    uint32_t tot = sh[255];
    uint32_t T0 = shB[0];
    uint32_t T1 = shB[1] - shB[0];
    uint32_t T2 = shB[2] - shB[1];
    uint32_t T3 = tot - shB[2];
    devOff[0] = 0;
    devOff[1] = devOff[0] + fiveN + 4LL * T0;
    devOff[2] = devOff[1] + fiveN + 4LL * T1;
    devOff[3] = devOff[2] + fiveN + 4LL * T2;
    devOff[4] = devOff[3] + fiveN + 4LL * T3;
    devRank[0] = 0;
    devRank[1] = shB[0];
    devRank[2] = shB[1];
    devRank[3] = shB[2];
  }
}

// k_pref: global-prefix pairs for s2/s4/s8 chunks (0..148) only
__global__ __launch_bounds__(256) void k_pref(
    const uint32_t* __restrict__ bitmap, const uint32_t* __restrict__ blockSums,
    uint2* __restrict__ pairs) {
  __shared__ uint32_t sh[256];
  int t = threadIdx.x;
  size_t w0 = (size_t)blockIdx.x * CHUNK + t * 16;
  const uint4* bp = (const uint4*)(bitmap + w0);
  uint4 words[4];
  uint32_t s = 0;
#pragma unroll
  for (int k = 0; k < 4; k++) {
    uint4 v = bp[k];
    words[k] = v;
    s += __popc(v.x) + __popc(v.y) + __popc(v.z) + __popc(v.w);
  }
  sh[t] = s;
  __syncthreads();
  for (int off = 1; off < 256; off <<= 1) {
    uint32_t add = (t >= off) ? sh[t - off] : 0u;
    __syncthreads();
    sh[t] += add;
    __syncthreads();
  }
  uint32_t run = blockSums[blockIdx.x] + (sh[t] - s);
  uint4* pp = (uint4*)(pairs + w0);
#pragma unroll
  for (int k = 0; k < 4; k++) {
    uint4 o1, o2;
    o1.x = words[k].x; o1.y = run; run += __popc(words[k].x);
    o1.z = words[k].y; o1.w = run; run += __popc(words[k].y);
    o2.x = words[k].z; o2.y = run; run += __popc(words[k].z);
    o2.z = words[k].w; o2.w = run; run += __popc(words[k].w);
    pp[2 * k] = o1;
    pp[2 * k + 1] = o2;
  }
}

// bit-decode of one word's set bits -> unique coors rows
template <int LZ, int LYZ, int LB, int MZ, int MY, int MX, int RG, int SCALE_IDX>
__device__ __forceinline__ void uniq_region(
    uint32_t w, uint32_t wd, uint32_t pf, uint32_t rankBase,
    const long long* __restrict__ devOff, int* __restrict__ out, long long fiveN) {
  uint32_t pos = pf - rankBase;
  long long base = devOff[SCALE_IDX] + fiveN;
  uint32_t local = w - (uint32_t)RG;
  while (wd) {
    int bit = __ffs(wd) - 1;
    wd &= wd - 1u;
    uint32_t key = (local << 5) + (uint32_t)bit;
    int z = (int)(key & (uint32_t)MZ);
    int y = (int)((key >> LZ) & (uint32_t)MY);
    int x = (int)((key >> LYZ) & (uint32_t)MX);
    int bb = (int)(key >> LB);
    *(int4*)(out + base + 4LL * pos) = make_int4(bb, z, y, x);
    pos++;
  }
}

// ---- merged outputs ----
// blocks [0, 4*NW):  per-scale write sections (s1,s2,s4,s8), 2 pts/thread
// blocks [4*NW, +TOTALW/256): unique-row decode
__global__ __launch_bounds__(256) void k_out(
    const uint32_t* __restrict__ keys, int n, const uint2* __restrict__ pairs,
    const uint32_t* __restrict__ devRank, const long long* __restrict__ devOff,
    const uint32_t* __restrict__ cs, int* __restrict__ out,
    long long fourN, long long fiveN, int NW) {
  int bid = blockIdx.x;
  int t = threadIdx.x;
  if (bid < 4 * NW) {
    int sec = bid / NW;
    int wb = bid - sec * NW;
    if (sec == 0) {
      // s1: pairs hold chunk-LOCAL prefixes; add cs[149 + (key>>17)]
      long long o = devOff[3];
      uint32_t rnk = devRank[3];
#pragma unroll
      for (int half = 0; half < 2; half++) {
        int j = wb * 512 + half * 256 + t;
        if (j >= n) continue;
        uint32_t p = keys[j];
        int b = (int)(p >> 27);
        int x1 = (int)((p >> 17) & 1023u);
        int y1 = (int)((p >> 7) & 1023u);
        int z1 = (int)(p & 127u);
        uint32_t key = (uint32_t)(((b * 512 + x1) * 512 + y1) * 64 + z1);
        uint2 pr = pairs[R_S1 + (key >> 5)];
        *(int4*)(out + o + 4LL * j) = make_int4(b, x1, y1, z1);
        uint32_t inv = cs[149 + (key >> 17)] + pr.y +
                       __popc(pr.x & ((1u << (key & 31u)) - 1u)) - rnk;
        out[o + fourN + j] = (int)inv;
      }
    } else {
      int i = sec - 1;                     // 0=s2, 1=s4, 2=s8
      const int SX[3] = {256, 128, 64};    // SY == SX
      const int SZ[3] = {32, 16, 8};
      const int SH[3] = {1, 2, 3};
      const int RG[3] = {R_S2, R_S4, R_S8};
      int sh = SH[i], sx = SX[i], sz = SZ[i], rg = RG[i];
      long long o = devOff[i];
      uint32_t rnk = devRank[i];
#pragma unroll
      for (int half = 0; half < 2; half++) {
        int j = wb * 512 + half * 256 + t;
        if (j >= n) continue;
        uint32_t p = keys[j];
        int b = (int)(p >> 27);
        int x1 = (int)((p >> 17) & 1023u);
        int y1 = (int)((p >> 7) & 1023u);
        int z1 = (int)(p & 127u);
        int xi = x1 >> sh, yi = y1 >> sh, zi = z1 >> sh;
        uint32_t key = (uint32_t)(((b * sx + xi) * sx + yi) * sz + zi);
        uint2 pr = pairs[rg + (key >> 5)];
        *(int4*)(out + o + 4LL * j) = make_int4(b, xi, yi, zi);
        uint32_t inv = pr.y + __popc(pr.x & ((1u << (key & 31u)) - 1u)) - rnk;
        out[o + fourN + j] = (int)inv;
      }
    }
  } else {
    uint32_t w = (uint32_t)(bid - 4 * NW) * 256 + t;  // < TOTALW, regions block-aligned
    uint2 pr = pairs[w];
    if (!pr.x) return;
    if (w < R_S4) {
      uniq_region<5, 13, 21, 31, 255, 255, R_S2, 0>(w, pr.x, pr.y, devRank[0], devOff, out, fiveN);
    } else if (w < R_S8) {
      uniq_region<4, 11, 18, 15, 127, 127, R_S4, 1>(w, pr.x, pr.y, devRank[1], devOff, out, fiveN);
    } else if (w < R_S1) {
      uniq_region<3, 9, 15, 7, 63, 63, R_S8, 2>(w, pr.x, pr.y, devRank[2], devOff, out, fiveN);
    } else {
      // s1: local prefix + chunk base
      uniq_region<6, 15, 24, 63, 511, 511, R_S1, 3>(
          w, pr.x, pr.y + cs[w >> 12], devRank[3], devOff, out, fiveN);
    }
  }
}

extern "C" void kernel_launch(void* const* d_in, const int* in_sizes, int n_in,
                              void* d_out, int out_size, void* d_ws, size_t ws_size,
                              hipStream_t stream) {
  const float* pts = (const float*)d_in[0];
  const int* bidx = (const int*)d_in[1];
  int n = in_sizes[0] / 3;
  int* out = (int*)d_out;

  char* ws = (char*)d_ws;
  long long* devOff = (long long*)ws;                          // 5 * 8 B
  uint32_t* devRank = (uint32_t*)(ws + 64);                    // 4 * 4 B
  uint32_t* chunkSums = (uint32_t*)(ws + 256);                 // NB * 4 B
  uint32_t* bucketCount = (uint32_t*)(ws + 5120);              // 512 * 4 B
  uint32_t* bitmap = (uint32_t*)(ws + 8192);                   // TOTALW * 4 B (s1 part unused)
  uint2* pairs = (uint2*)(ws + 19243008);                      // TOTALW * 8 B
  uint32_t* keys = (uint32_t*)(ws + 57712640);                 // n * 4 B
  uint32_t* bucketData = (uint32_t*)(ws + 65712640);           // 512 * BCAP * 4 B

  const long long fourN = 4LL * n, fiveN = 5LL * n;
  const int NW = (n + 511) / 512;

  hipMemsetAsync(bucketCount, 0, NBUCKET * 4, stream);
  hipLaunchKernelGGL(k_key, dim3(KEYBLOCKS), dim3(256), 0, stream,
                     pts, bidx, n, keys, bucketCount, bucketData, chunkSums);
  hipLaunchKernelGGL(k_bucket, dim3(NBUCKET), dim3(256), 0, stream,
                     bucketCount, bucketData, bitmap, chunkSums, pairs);
  hipLaunchKernelGGL(k_scanB, dim3(1), dim3(256), 0, stream, chunkSums, devOff, devRank, fiveN);
  hipLaunchKernelGGL(k_pref, dim3(NB_SMALL), dim3(256), 0, stream, bitmap, chunkSums, pairs);
  hipLaunchKernelGGL(k_out, dim3(4 * NW + TOTALW / 256), dim3(256), 0, stream,
                     keys, n, pairs, devRank, devOff, chunkSums, out, fourN, fiveN, NW);
}

// Round 8
// 422.714 us; speedup vs baseline: 1.0481x; 1.0110x over previous
//
#include <hip/hip_runtime.h>
#include <stdint.h>

// Voxelization, scales {2,4,8,1}.
//  - pow2 dims => scale-s index == scale-1 index >> log2(s), bit-exact in f32
//  - k_key: packed keys + partition s1 keys into 512 spatial buckets.
//  - k_bucket (R11): builds s1 region in LDS, derives s2/s4/s8 in-LDS, and
//    emits PAIRS (bits + BUCKET-LOCAL prefix) for ALL four scales directly.
//    Per-bucket totals -> sums[2560] via plain stores (no atomics, no init).
//    Bitmap buffer and k_pref dispatch deleted.
//  - k_scanB: scans sums -> zero-based per-bucket bases[2560] + devOff.
//  - k_out: R4-proven per-scale sections, 2 pts/thread (coalesced stores);
//    rank = bases[bucket] + local prefix + popc. bases is 10KB, L1-resident.
// Dispatches: memset(bucketCount), key, bucket, scanB, out.  (5 total)

#define TOTALW 4808704
// region word offsets, scale order {2,4,8,1}
#define R_S2 0
#define R_S4 528384
#define R_S8 598016
#define R_S1 610304
// pad word ranges (4096 words each), zeroed in PAIRS by k_bucket blocks 0..3
#define PAD0 524288
#define PAD1 593920
#define PAD2 606208
#define PAD3 4804608
// bucketing: 512 buckets; per bucket: s2 1024 words, s4 128, s8 16, s1 8192
#define NBUCKET 512
#define BCAP 5120
// sums/bases layout: [0,512)=s2, [512,1024)=s4, [1024,1536)=s8,
// [1536,2560)=s1 half-buckets (2 per bucket)
#define NSUM 2560
// 1024 blocks x 2048 points, 8 keys/thread
#define KEYBLOCKS 1024
#define ROUND 2048
#define KPT 8

__device__ __forceinline__ uint32_t cmp2(uint32_t w) {
  // result bit i = w[2i] | w[2i+1]  (32->16; also 16->8 with zero upper)
  w = (w | (w >> 1)) & 0x55555555u;
  w = (w | (w >> 1)) & 0x33333333u;
  w = (w | (w >> 2)) & 0x0F0F0F0Fu;
  w = (w | (w >> 4)) & 0x00FF00FFu;
  w = (w | (w >> 8)) & 0x0000FFFFu;
  return w;
}

// inclusive 256-scan over shR; leading barrier protects prior-phase readers
__device__ __forceinline__ uint32_t scan256(uint32_t v, uint32_t* shR, int t) {
  __syncthreads();
  shR[t] = v;
  __syncthreads();
  for (int off = 1; off < 256; off <<= 1) {
    uint32_t add = (t >= off) ? shR[t - off] : 0u;
    __syncthreads();
    shR[t] += add;
    __syncthreads();
  }
  return shR[t];
}

// ---- phase 1: keys + bucket partition ----
__global__ __launch_bounds__(256) void k_key(
    const float* __restrict__ pts, const int* __restrict__ bidx, int n,
    uint32_t* __restrict__ keys,
    uint32_t* __restrict__ bucketCount, uint32_t* __restrict__ bucketData) {
  __shared__ uint32_t cnt[NBUCKET], inc[NBUCKET], pos[NBUCKET], gpos[NBUCKET];
  __shared__ uint32_t shs[256];
  __shared__ uint32_t scratch[ROUND];
  int t = threadIdx.x;
  int base = blockIdx.x * ROUND;

  cnt[t] = 0; cnt[t + 256] = 0;
  pos[t] = 0; pos[t + 256] = 0;
  __syncthreads();

  uint32_t myKey[KPT];
  int myBk[KPT];
#pragma unroll
  for (int k = 0; k < KPT; k++) {
    int j = base + k * 256 + t;
    myBk[k] = -1;
    if (j < n) {
      float px = pts[3 * j + 0];
      float py = pts[3 * j + 1];
      float pz = pts[3 * j + 2];
      int b = bidx[j];
      // exact reference arithmetic at scale 1 (f32 mul, add, div, trunc)
      int x1 = (int)((512.0f * (px + 51.2f)) / 102.4f);
      int y1 = (int)((512.0f * (py + 51.2f)) / 102.4f);
      int z1 = (int)((64.0f * (pz + 4.0f)) / 6.4f);
      keys[j] = ((uint32_t)b << 27) | ((uint32_t)x1 << 17) | ((uint32_t)y1 << 7) | (uint32_t)z1;
      uint32_t s1k = (uint32_t)(((b * 512 + x1) * 512 + y1) * 64 + z1);
      if (s1k < (1u << 27)) {  // always true for in-spec inputs; OOB-guard only
        int bk = (int)(s1k >> 18);
        myBk[k] = bk;
        myKey[k] = s1k;
        atomicAdd(&cnt[bk], 1u);
      }
    }
  }
  __syncthreads();

  // global reservation (cnt final)
  uint32_t c0 = cnt[2 * t], c1 = cnt[2 * t + 1];
  gpos[2 * t] = c0 ? atomicAdd(&bucketCount[2 * t], c0) : 0u;
  gpos[2 * t + 1] = c1 ? atomicAdd(&bucketCount[2 * t + 1], c1) : 0u;
  // inclusive scan of cnt -> inc (pairwise + 256-scan)
  uint32_t s = c0 + c1;
  shs[t] = s;
  __syncthreads();
  for (int off = 1; off < 256; off <<= 1) {
    uint32_t add = (t >= off) ? shs[t - off] : 0u;
    __syncthreads();
    shs[t] += add;
    __syncthreads();
  }
  inc[2 * t] = shs[t] - s + c0;
  inc[2 * t + 1] = shs[t];
  __syncthreads();
  uint32_t total = shs[255];

  // scatter into bucket-contiguous LDS scratch
#pragma unroll
  for (int k = 0; k < KPT; k++) {
    if (myBk[k] >= 0) {
      int bk = myBk[k];
      uint32_t slot = inc[bk] - cnt[bk] + atomicAdd(&pos[bk], 1u);
      scratch[slot] = myKey[k];
    }
  }
  __syncthreads();

  // flush: consecutive p -> contiguous global per bucket; bucket id from key
#pragma unroll
  for (int m = 0; m < KPT; m++) {
    uint32_t p = (uint32_t)(m * 256 + t);
    if (p < total) {
      uint32_t kk = scratch[p];
      int lo = (int)(kk >> 18);
      uint32_t lidx = p - (inc[lo] - cnt[lo]);
      uint32_t g = gpos[lo] + lidx;
      if (g < BCAP) bucketData[(size_t)lo * BCAP + g] = kk;
    }
  }
}

// ---- phase 2: per-bucket LDS build + downsample + ALL pairs + sums ----
__global__ __launch_bounds__(256) void k_bucket(
    const uint32_t* __restrict__ bucketCount, const uint32_t* __restrict__ bucketData,
    uint32_t* __restrict__ sums, uint2* __restrict__ pairs) {
  __shared__ uint32_t s1L[8192];
  __shared__ uint32_t s2L[1024];
  __shared__ uint32_t s4L[128];
  __shared__ uint32_t shR[256];
  int bk = blockIdx.x, t = threadIdx.x;

  uint4 z4 = make_uint4(0, 0, 0, 0);
  for (int i = t; i < 2048; i += 256) ((uint4*)s1L)[i] = z4;

  // zero pad PAIRS (4096 pairs = 2048 uint4 per pad region), blocks 0..3
  if (bk < 4) {
    const int pads[4] = {PAD0, PAD1, PAD2, PAD3};
    uint4* pz = (uint4*)(pairs + pads[bk]);
    for (int i = t; i < 2048; i += 256) pz[i] = z4;
  }
  __syncthreads();

  uint32_t c = bucketCount[bk];
  if (c > BCAP) c = BCAP;
  const uint32_t* src = bucketData + (size_t)bk * BCAP;
  for (uint32_t i = t; i < c; i += 256) {
    uint32_t key = src[i];
    uint32_t local = key & 0x3FFFFu;  // 2^18 bits per bucket
    atomicOr(&s1L[local >> 5], 1u << (local & 31u));
  }
  __syncthreads();

  // ---- s1 pairs: thread t owns words [32t, 32t+32); half-bucket-local prefix
  uint32_t wsum = 0;
#pragma unroll
  for (int m = 0; m < 8; m++) {
    uint4 v = ((uint4*)s1L)[8 * t + m];
    wsum += __popc(v.x) + __popc(v.y) + __popc(v.z) + __popc(v.w);
  }
  uint32_t incl1 = scan256(wsum, shR, t);
  uint32_t S1a = shR[127];
  uint32_t S1tot = shR[255];
  uint32_t run = incl1 - wsum;        // exclusive prefix
  if (t >= 128) run -= S1a;           // reset at half-bucket boundary
  {
    uint4* pb = (uint4*)(pairs + (R_S1 + (size_t)bk * 8192));
#pragma unroll
    for (int m = 0; m < 8; m++) {
      uint4 v = ((uint4*)s1L)[8 * t + m];
      uint32_t r0 = run;               uint32_t p0 = __popc(v.x);
      uint32_t r1 = r0 + p0;           uint32_t p1 = __popc(v.y);
      uint32_t r2 = r1 + p1;           uint32_t p2 = __popc(v.z);
      uint32_t r3 = r2 + p2;           run = r3 + __popc(v.w);
      int q = (32 * t + 4 * m) >> 1;   // uint4 index into pairs
      pb[q + 0] = make_uint4(v.x, r0, v.y, r1);
      pb[q + 1] = make_uint4(v.z, r2, v.w, r3);
    }
  }

  // ---- s2 from s1 (s1 word = (x1rel*512 + y1)*2 + h, x1rel in [0,8)) ----
  for (int i = t; i < 1024; i += 256) {
    int x2r = i >> 8, Y2 = i & 255;
    int a = (2 * x2r * 512 + 2 * Y2) * 2;
    int b2 = ((2 * x2r + 1) * 512 + 2 * Y2) * 2;
    uint32_t Ax = s1L[a], Ay = s1L[a + 1], Az = s1L[a + 2], Aw = s1L[a + 3];
    uint32_t Bx = s1L[b2], By = s1L[b2 + 1], Bz = s1L[b2 + 2], Bw = s1L[b2 + 3];
    s2L[i] = cmp2(Ax | Az | Bx | Bz) | (cmp2(Ay | Aw | By | Bw) << 16);
  }
  __syncthreads();
  // s2 pairs: thread t owns words [4t, 4t+4)
  uint32_t a0 = s2L[4 * t], a1 = s2L[4 * t + 1], a2 = s2L[4 * t + 2], a3 = s2L[4 * t + 3];
  uint32_t sum2 = __popc(a0) + __popc(a1) + __popc(a2) + __popc(a3);
  uint32_t incl2 = scan256(sum2, shR, t);
  uint32_t S2tot = shR[255];
  uint32_t run2 = incl2 - sum2;
  {
    uint4* pb = (uint4*)(pairs + (R_S2 + (size_t)bk * 1024));
    uint32_t r1 = run2 + __popc(a0);
    uint32_t r2 = r1 + __popc(a1);
    uint32_t r3 = r2 + __popc(a2);
    pb[2 * t + 0] = make_uint4(a0, run2, a1, r1);
    pb[2 * t + 1] = make_uint4(a2, r2, a3, r3);
  }

  // ---- s4 from s2 (s2 local: x2rel*256 + y2, x2rel in [0,4)) ----
  uint32_t v4 = 0;
  if (t < 128) {
    int x4r = t >> 6, kk = t & 63;
    int a = (2 * x4r) * 256 + 4 * kk;
    int b4 = (2 * x4r + 1) * 256 + 4 * kk;
    uint32_t A0 = s2L[a], A1 = s2L[a + 1], A2 = s2L[a + 2], A3 = s2L[a + 3];
    uint32_t B0 = s2L[b4], B1 = s2L[b4 + 1], B2 = s2L[b4 + 2], B3 = s2L[b4 + 3];
    v4 = cmp2(A0 | A1 | B0 | B1) | (cmp2(A2 | A3 | B2 | B3) << 16);
    s4L[t] = v4;
  }
  uint32_t incl4 = scan256(__popc(v4), shR, t);
  uint32_t S4tot = shR[255];
  uint32_t run4 = incl4 - __popc(v4);
  if (t < 128) pairs[R_S4 + (size_t)bk * 128 + t] = make_uint2(v4, run4);

  // ---- s8 from s4 (s4 local: x4rel*64 + kk, x4rel in {0,1}) ----
  uint32_t v8 = 0;
  if (t < 16) {
#pragma unroll
    for (int j = 0; j < 4; j++) {
      uint32_t u = s4L[4 * t + j] | s4L[64 + 4 * t + j];
      u = (u | (u >> 16)) & 0xFFFFu;
      v8 |= cmp2(u) << (8 * j);
    }
  }
  uint32_t incl8 = scan256(__popc(v8), shR, t);
  uint32_t S8tot = shR[255];
  uint32_t run8 = incl8 - __popc(v8);
  if (t < 16) pairs[R_S8 + (size_t)bk * 16 + t] = make_uint2(v8, run8);

  // per-bucket totals: plain stores (each bucket owns its slots)
  if (t == 0) {
    sums[bk] = S2tot;
    sums[512 + bk] = S4tot;
    sums[1024 + bk] = S8tot;
    sums[1536 + 2 * bk] = S1a;
    sums[1537 + 2 * bk] = S1tot - S1a;
  }
}

// ---- scan sums -> zero-based per-bucket bases + devOff ----
__global__ __launch_bounds__(256) void k_scanB(
    const uint32_t* __restrict__ sums, uint32_t* __restrict__ bases,
    long long* __restrict__ devOff, long long fiveN) {
  __shared__ uint32_t sh[256];
  __shared__ uint32_t shB[3];
  int t = threadIdx.x;
  uint32_t v[10];
  uint32_t s = 0;
#pragma unroll
  for (int k = 0; k < 10; k++) {
    int idx = t * 10 + k;
    uint32_t x = sums[idx];
    v[k] = x;
    s += x;
  }
  sh[t] = s;
  __syncthreads();
  for (int off = 1; off < 256; off <<= 1) {
    uint32_t add = (t >= off) ? sh[t - off] : 0u;
    __syncthreads();
    sh[t] += add;
    __syncthreads();
  }
  // pass 1: capture scale-boundary exclusive prefixes
  uint32_t run = sh[t] - s;
#pragma unroll
  for (int k = 0; k < 10; k++) {
    int idx = t * 10 + k;
    if (idx == 512) shB[0] = run;
    if (idx == 1024) shB[1] = run;
    if (idx == 1536) shB[2] = run;
    run += v[k];
  }
  __syncthreads();
  // pass 2: zero-based bases per scale
  uint32_t B0 = shB[0], B1 = shB[1], B2 = shB[2];
  run = sh[t] - s;
#pragma unroll
  for (int k = 0; k < 10; k++) {
    int idx = t * 10 + k;
    uint32_t sub = (idx < 512) ? 0u : (idx < 1024) ? B0 : (idx < 1536) ? B1 : B2;
    bases[idx] = run - sub;
    run += v[k];
  }
  if (t == 0) {
    uint32_t tot = sh[255];
    uint32_t T0 = B0;           // s2 total
    uint32_t T1 = B1 - B0;      // s4 total
    uint32_t T2 = B2 - B1;      // s8 total
    uint32_t T3 = tot - B2;     // s1 total
    devOff[0] = 0;
    devOff[1] = devOff[0] + fiveN + 4LL * T0;
    devOff[2] = devOff[1] + fiveN + 4LL * T1;
    devOff[3] = devOff[2] + fiveN + 4LL * T2;
    devOff[4] = devOff[3] + fiveN + 4LL * T3;
  }
}

// bit-decode of one word's set bits -> unique coors rows (pf already based)
template <int LZ, int LYZ, int LB, int MZ, int MY, int MX, int RG, int SCALE_IDX>
__device__ __forceinline__ void uniq_region(
    uint32_t w, uint32_t wd, uint32_t pf,
    const long long* __restrict__ devOff, int* __restrict__ out, long long fiveN) {
  uint32_t pos = pf;
  long long base = devOff[SCALE_IDX] + fiveN;
  uint32_t local = w - (uint32_t)RG;
  while (wd) {
    int bit = __ffs(wd) - 1;
    wd &= wd - 1u;
    uint32_t key = (local << 5) + (uint32_t)bit;
    int z = (int)(key & (uint32_t)MZ);
    int y = (int)((key >> LZ) & (uint32_t)MY);
    int x = (int)((key >> LYZ) & (uint32_t)MX);
    int bb = (int)(key >> LB);
    *(int4*)(out + base + 4LL * pos) = make_int4(bb, z, y, x);
    pos++;
  }
}

// ---- merged outputs ----
// blocks [0, 4*NW):  per-scale write sections (s1,s2,s4,s8), 2 pts/thread
// blocks [4*NW, +TOTALW/256): unique-row decode
__global__ __launch_bounds__(256) void k_out(
    const uint32_t* __restrict__ keys, int n, const uint2* __restrict__ pairs,
    const uint32_t* __restrict__ bs, const long long* __restrict__ devOff,
    int* __restrict__ out, long long fourN, long long fiveN, int NW) {
  int bid = blockIdx.x;
  int t = threadIdx.x;
  if (bid < 4 * NW) {
    int sec = bid / NW;
    int wb = bid - sec * NW;
    if (sec == 0) {
      // s1: rank = bs[1536 + key>>17] + local prefix + popc
      long long o = devOff[3];
#pragma unroll
      for (int half = 0; half < 2; half++) {
        int j = wb * 512 + half * 256 + t;
        if (j >= n) continue;
        uint32_t p = keys[j];
        int b = (int)(p >> 27);
        int x1 = (int)((p >> 17) & 1023u);
        int y1 = (int)((p >> 7) & 1023u);
        int z1 = (int)(p & 127u);
        uint32_t key = (uint32_t)(((b * 512 + x1) * 512 + y1) * 64 + z1);
        uint2 pr = pairs[R_S1 + (key >> 5)];
        *(int4*)(out + o + 4LL * j) = make_int4(b, x1, y1, z1);
        uint32_t inv = bs[1536 + (key >> 17)] + pr.y +
                       __popc(pr.x & ((1u << (key & 31u)) - 1u));
        out[o + fourN + j] = (int)inv;
      }
    } else {
      int i = sec - 1;                     // 0=s2, 1=s4, 2=s8
      const int SX[3] = {256, 128, 64};    // SY == SX
      const int SZ[3] = {32, 16, 8};
      const int SH[3] = {1, 2, 3};
      const int RG[3] = {R_S2, R_S4, R_S8};
      const int BO[3] = {0, 512, 1024};    // bases offset
      const int BS[3] = {15, 12, 9};       // key -> bucket shift
      int sh = SH[i], sx = SX[i], sz = SZ[i], rg = RG[i];
      long long o = devOff[i];
#pragma unroll
      for (int half = 0; half < 2; half++) {
        int j = wb * 512 + half * 256 + t;
        if (j >= n) continue;
        uint32_t p = keys[j];
        int b = (int)(p >> 27);
        int x1 = (int)((p >> 17) & 1023u);
        int y1 = (int)((p >> 7) & 1023u);
        int z1 = (int)(p & 127u);
        int xi = x1 >> sh, yi = y1 >> sh, zi = z1 >> sh;
        uint32_t key = (uint32_t)(((b * sx + xi) * sx + yi) * sz + zi);
        uint2 pr = pairs[rg + (key >> 5)];
        *(int4*)(out + o + 4LL * j) = make_int4(b, xi, yi, zi);
        uint32_t inv = bs[BO[i] + (key >> BS[i])] + pr.y +
                       __popc(pr.x & ((1u << (key & 31u)) - 1u));
        out[o + fourN + j] = (int)inv;
      }
    }
  } else {
    uint32_t w = (uint32_t)(bid - 4 * NW) * 256 + t;  // < TOTALW, regions block-aligned
    uint2 pr = pairs[w];
    if (!pr.x) return;
    if (w < R_S4) {
      uniq_region<5, 13, 21, 31, 255, 255, R_S2, 0>(
          w, pr.x, pr.y + bs[w >> 10], devOff, out, fiveN);
    } else if (w < R_S8) {
      uniq_region<4, 11, 18, 15, 127, 127, R_S4, 1>(
          w, pr.x, pr.y + bs[512 + ((w - R_S4) >> 7)], devOff, out, fiveN);
    } else if (w < R_S1) {
      uniq_region<3, 9, 15, 7, 63, 63, R_S8, 2>(
          w, pr.x, pr.y + bs[1024 + ((w - R_S8) >> 4)], devOff, out, fiveN);
    } else {
      uniq_region<6, 15, 24, 63, 511, 511, R_S1, 3>(
          w, pr.x, pr.y + bs[1536 + ((w - R_S1) >> 12)], devOff, out, fiveN);
    }
  }
}

extern "C" void kernel_launch(void* const* d_in, const int* in_sizes, int n_in,
                              void* d_out, int out_size, void* d_ws, size_t ws_size,
                              hipStream_t stream) {
  const float* pts = (const float*)d_in[0];
  const int* bidx = (const int*)d_in[1];
  int n = in_sizes[0] / 3;
  int* out = (int*)d_out;

  char* ws = (char*)d_ws;
  long long* devOff = (long long*)ws;                          // 5 * 8 B
  uint32_t* sums = (uint32_t*)(ws + 256);                      // 2560 * 4 B
  uint32_t* bases = (uint32_t*)(ws + 12288);                   // 2560 * 4 B
  uint32_t* bucketCount = (uint32_t*)(ws + 24576);             // 512 * 4 B
  uint2* pairs = (uint2*)(ws + 19243008);                      // TOTALW * 8 B
  uint32_t* keys = (uint32_t*)(ws + 57712640);                 // n * 4 B
  uint32_t* bucketData = (uint32_t*)(ws + 65712640);           // 512 * BCAP * 4 B

  const long long fourN = 4LL * n, fiveN = 5LL * n;
  const int NW = (n + 511) / 512;

  hipMemsetAsync(bucketCount, 0, NBUCKET * 4, stream);
  hipLaunchKernelGGL(k_key, dim3(KEYBLOCKS), dim3(256), 0, stream,
                     pts, bidx, n, keys, bucketCount, bucketData);
  hipLaunchKernelGGL(k_bucket, dim3(NBUCKET), dim3(256), 0, stream,
                     bucketCount, bucketData, sums, pairs);
  hipLaunchKernelGGL(k_scanB, dim3(1), dim3(256), 0, stream,
                     sums, bases, devOff, fiveN);
  hipLaunchKernelGGL(k_out, dim3(4 * NW + TOTALW / 256), dim3(256), 0, stream,
                     keys, n, pairs, bases, devOff, out, fourN, fiveN, NW);
}